// Round 22
// baseline (243.197 us; speedup 1.0000x reference)
//
#include <hip/hip_runtime.h>
#include <hip/hip_fp16.h>
#include <math.h>

#define EMB 32
#define HID 16
#define BY 4
#define NSYMP 15
#define NOPT 3
#define XCOLS (BY + 1 + NSYMP)   // 20

#define BSHIFT 8                 // 256 nodes per tgt bucket
#define BSZ 256
#define EPB 8192                 // edges per scat block (gb1 = 782)
#define NBCAP 1024               // padded bin capacity (>= nbuck+1 = 783)
#define SPT 4                    // scan items per thread in scat (1024/256)
#define SPT2 2                   // segments per thread in bcsr (512 thr, covers gb1 <= 1024)
#define LSTCAP 9216              // staged edges per bucket (mean 8184, +11 sigma)

__device__ __forceinline__ unsigned int wave_incl_scan(unsigned int v, int lane) {
#pragma unroll
    for (int off = 1; off < 64; off <<= 1) {
        unsigned int u = __shfl_up(v, off, 64);
        if (lane >= off) v += u;
    }
    return v;
}

// ---- fused hist + local scan + block-local scatter ----
__global__ __launch_bounds__(256) void k_scat(const int* __restrict__ tgt,
                                              const int* __restrict__ src,
                                              unsigned int* __restrict__ L,
                                              int* __restrict__ bp,
                                              int nE, int gb1, int nbuck) {
    __shared__ int bpv[EPB];                 // 32 KB staged payload
    __shared__ unsigned int cur[NBCAP];      // 4 KB hist -> cursors
    __shared__ unsigned int wsum[4];
    int b = blockIdx.x, tid = threadIdx.x;
    int lane = tid & 63, wid = tid >> 6;
    for (int k = tid; k < NBCAP; k += 256) cur[k] = 0;
    __syncthreads();
    int e0 = b * EPB;
    int ecnt = min(EPB, nE - e0);

    for (int k = tid; k < ecnt; k += 256)
        atomicAdd(&cur[(unsigned)tgt[e0 + k] >> BSHIFT], 1u);
    __syncthreads();

    unsigned int lv[SPT]; unsigned int tsum = 0;
#pragma unroll
    for (int k = 0; k < SPT; ++k) {
        int f = SPT * tid + k;
        lv[k] = tsum; tsum += cur[f];
    }
    unsigned int incl = wave_incl_scan(tsum, lane);
    if (lane == 63) wsum[wid] = incl;
    __syncthreads();
    unsigned int woff = 0;
    for (int w = 0; w < wid; ++w) woff += wsum[w];
    unsigned int excl = woff + incl - tsum;
    __syncthreads();
#pragma unroll
    for (int k = 0; k < SPT; ++k) {
        int f = SPT * tid + k;
        unsigned int v = excl + lv[k];
        cur[f] = v;
        if (f <= nbuck) L[(size_t)f * gb1 + b] = v;
    }
    __syncthreads();

    for (int k = tid; k < ecnt; k += 256) {
        int t = tgt[e0 + k];
        int q = (unsigned)t >> BSHIFT;
        unsigned int lpos = atomicAdd(&cur[q], 1u);
        bpv[lpos] = (src[e0 + k] << BSHIFT) | (t & (BSZ - 1));
    }
    __syncthreads();

    for (int k = tid; k < ecnt; k += 256)
        bp[e0 + k] = bpv[k];
}

// ---- row sums of L -> global bucket starts R[q] ----
__global__ __launch_bounds__(256) void k_rsum(const unsigned int* __restrict__ L,
                                              unsigned int* __restrict__ R, int gb1) {
    __shared__ unsigned int s[256];
    int q = blockIdx.x, tid = threadIdx.x;
    unsigned int t = 0;
    for (int b = tid; b < gb1; b += 256) t += L[(size_t)q * gb1 + b];
    s[tid] = t; __syncthreads();
    for (int off = 128; off > 0; off >>= 1) {
        if (tid < off) s[tid] += s[tid + off];
        __syncthreads();
    }
    if (tid == 0) R[q] = s[0];
}

// ---- level-2 + embed fusion: R20 code shape; embed tables read via L1
//      (no LDS staging) -> 38.5 KB LDS -> 4 blocks/CU at ~56 VGPR ----
__global__ __launch_bounds__(512) void k_bcsr(const unsigned int* __restrict__ L,
                                              const unsigned int* __restrict__ R,
                                              const int* __restrict__ bp,
                                              const int* __restrict__ x,
                                              const float* __restrict__ birth_t,
                                              const float* __restrict__ gender_t,
                                              const float* __restrict__ symp_t,
                                              const float* __restrict__ W1,
                                              unsigned int* __restrict__ rowptr,
                                              int* __restrict__ col,
                                              float* __restrict__ dinv,
                                              __half* __restrict__ A16,
                                              int n, int gb1) {
    __shared__ int lst[LSTCAP];              // 36 KB
    __shared__ unsigned int h[BSZ];
    __shared__ unsigned int cu[BSZ];
    __shared__ unsigned int wsum[8];
    int q = blockIdx.x, tid = threadIdx.x;
    int lane = tid & 63, wid = tid >> 6;
    if (tid < BSZ) h[tid] = 0;

    const unsigned int* Lq0 = L + (size_t)q * gb1;
    const unsigned int* Lq1 = L + (size_t)(q + 1) * gb1;

    // phase A: per-thread segment lengths + prefix
    unsigned int st_[SPT2], ln_[SPT2], lvb[SPT2];
    unsigned int tsum = 0;
#pragma unroll
    for (int k = 0; k < SPT2; ++k) {
        int b = tid * SPT2 + k;
        unsigned int st = 0, ln = 0;
        if (b < gb1) { st = Lq0[b]; ln = Lq1[b] - st; }
        st_[k] = st; ln_[k] = ln; lvb[k] = tsum; tsum += ln;
    }
    unsigned int incl = wave_incl_scan(tsum, lane);
    if (lane == 63) wsum[wid] = incl;
    __syncthreads();                         // h[] init + wsum ready
    unsigned int woff = 0;
    for (int w = 0; w < wid; ++w) woff += wsum[w];
    unsigned int base = woff + incl - tsum;

    // copy + FUSED fine hist (4-wide, R20 shape)
#pragma unroll
    for (int k = 0; k < SPT2; ++k) {
        const int* sp = bp + (size_t)(tid * SPT2 + k) * EPB + st_[k];
        unsigned int d = base + lvb[k];
        unsigned int ln = ln_[k];
        unsigned int j = 0;
        for (; j + 4 <= ln; j += 4) {
            int v0 = sp[j], v1 = sp[j + 1], v2 = sp[j + 2], v3 = sp[j + 3];
            lst[d + j] = v0; lst[d + j + 1] = v1;
            lst[d + j + 2] = v2; lst[d + j + 3] = v3;
            atomicAdd(&h[v0 & (BSZ - 1)], 1u);
            atomicAdd(&h[v1 & (BSZ - 1)], 1u);
            atomicAdd(&h[v2 & (BSZ - 1)], 1u);
            atomicAdd(&h[v3 & (BSZ - 1)], 1u);
        }
        for (; j < ln; ++j) {
            int v = sp[j];
            lst[d + j] = v;
            atomicAdd(&h[v & (BSZ - 1)], 1u);
        }
    }
    __syncthreads();

    unsigned int r0g = R[q];
    int cnt = (int)(R[q + 1] - r0g);

    // scan h -> cursors, rowptr, dinv
    float dvreg = 0.f;
    if (tid < BSZ) {
        unsigned int own = h[tid];
        unsigned int incl2 = wave_incl_scan(own, lane);
        if (lane == 63) wsum[wid] = incl2;
        cu[tid] = incl2 - own;   // wave-local exclusive
    }
    __syncthreads();
    if (tid < BSZ) {
        unsigned int woff2 = 0;
        for (int w = 0; w < wid; ++w) woff2 += wsum[w];
        unsigned int excl = woff2 + cu[tid];
        cu[tid] = excl;
        unsigned int own = h[tid];
        int i = (q << BSHIFT) + tid;
        if (i <= n) rowptr[i] = r0g + excl;
        if (i < n) {
            float d = (float)(own + 1u);
            float r = rsqrtf(d);
            r = r * (1.5f - 0.5f * d * r * r);
            dinv[i] = r;
            dvreg = r;
        }
    }
    __syncthreads();

    // phase C: scatter to col (4-wide) from lst
    {
        int k = tid;
        for (; k + 3 * 512 < cnt; k += 4 * 512) {
            int v0 = lst[k], v1 = lst[k + 512], v2 = lst[k + 1024], v3 = lst[k + 1536];
            unsigned int p0 = atomicAdd(&cu[v0 & (BSZ - 1)], 1u);
            unsigned int p1 = atomicAdd(&cu[v1 & (BSZ - 1)], 1u);
            unsigned int p2 = atomicAdd(&cu[v2 & (BSZ - 1)], 1u);
            unsigned int p3 = atomicAdd(&cu[v3 & (BSZ - 1)], 1u);
            col[r0g + p0] = (unsigned)v0 >> BSHIFT;
            col[r0g + p1] = (unsigned)v1 >> BSHIFT;
            col[r0g + p2] = (unsigned)v2 >> BSHIFT;
            col[r0g + p3] = (unsigned)v3 >> BSHIFT;
        }
        for (; k < cnt; k += 512) {
            int v = lst[k];
            unsigned int pos = atomicAdd(&cu[v & (BSZ - 1)], 1u);
            col[r0g + pos] = (unsigned)v >> BSHIFT;
        }
    }

    // phase D: embedding + h@W1 (R20 scalar shape; tables via L1)
    if (tid < BSZ) {
        int i = (q << BSHIFT) + tid;
        if (i < n) {
            const int* xr = x + (size_t)i * XCOLS;
            int xv[XCOLS];
#pragma unroll
            for (int k = 0; k < XCOLS; ++k) xv[k] = xr[k];
            int bi = 0;
#pragma unroll
            for (int k = 1; k < BY; ++k) if (xv[k] > xv[bi]) bi = k;
            int gi = xv[BY];
            float ssum[EMB];
#pragma unroll
            for (int k = 0; k < EMB; ++k) ssum[k] = 0.f;
#pragma unroll
            for (int j = 0; j < NSYMP; ++j) {
                const float* row = &symp_t[(j * NOPT + xv[BY + 1 + j]) * EMB];
#pragma unroll
                for (int k = 0; k < EMB; ++k) ssum[k] += row[k];
            }
            float hh[EMB];
#pragma unroll
            for (int k = 0; k < EMB; ++k)
                hh[k] = (birth_t[bi * EMB + k] + gender_t[gi * EMB + k] + ssum[k] * (1.f / 15.f)) * (1.f / 3.f);
            float hp[HID];
#pragma unroll
            for (int j = 0; j < HID; ++j) hp[j] = 0.f;
#pragma unroll
            for (int k = 0; k < EMB; ++k) {
                float hv = hh[k];
#pragma unroll
                for (int j = 0; j < HID; ++j) hp[j] += hv * W1[k * HID + j];
            }
            __half2 t2[8];
#pragma unroll
            for (int j = 0; j < 8; ++j)
                t2[j] = __floats2half2_rn(dvreg * hp[2 * j], dvreg * hp[2 * j + 1]);
            uint4* o = (uint4*)(A16 + (size_t)i * HID);
            o[0] = *(uint4*)&t2[0];
            o[1] = *(uint4*)&t2[4];
        }
    }
}

// ---- layer 1: lane-pair fp16 CSR gather (4 rows in flight) + ELU + W2 + z ----
__global__ __launch_bounds__(256) void k_gmid5(const unsigned int* __restrict__ rowptr,
                                               const int* __restrict__ col,
                                               const __half* __restrict__ A16,
                                               const float* __restrict__ dinv,
                                               const float* __restrict__ W2,
                                               const float* __restrict__ b1,
                                               const float* __restrict__ Wl,
                                               float* __restrict__ z, int n) {
    __shared__ float sW[HID * HID];
    __shared__ float sb[HID];
    __shared__ float sw[HID];
    __shared__ float sAcc[16][HID];
    if (threadIdx.x < HID * HID) sW[threadIdx.x] = W2[threadIdx.x];
    if (threadIdx.x < HID) { sb[threadIdx.x] = b1[threadIdx.x]; sw[threadIdx.x] = Wl[threadIdx.x]; }
    __syncthreads();

    int gg = threadIdx.x >> 4;
    int l  = threadIdx.x & 15;
    int p  = l >> 1;
    int hc = l & 1;
    int i = blockIdx.x * 16 + gg;
    bool valid = (i < n);

    unsigned int r0 = 0, r1 = 0;
    if (valid) { r0 = rowptr[i]; r1 = rowptr[i + 1]; }

    float a[8];
#pragma unroll
    for (int k = 0; k < 8; ++k) a[k] = 0.f;

    unsigned int e = r0;
    for (; e + 32 <= r1; e += 32) {
        int s0 = col[e + p];
        int s1 = col[e + 8 + p];
        int s2 = col[e + 16 + p];
        int s3 = col[e + 24 + p];
        uint4 raw0 = *((const uint4*)(A16 + (size_t)s0 * HID) + hc);
        uint4 raw1 = *((const uint4*)(A16 + (size_t)s1 * HID) + hc);
        uint4 raw2 = *((const uint4*)(A16 + (size_t)s2 * HID) + hc);
        uint4 raw3 = *((const uint4*)(A16 + (size_t)s3 * HID) + hc);
        const __half2* h0 = (const __half2*)&raw0;
        const __half2* h1 = (const __half2*)&raw1;
        const __half2* h2 = (const __half2*)&raw2;
        const __half2* h3 = (const __half2*)&raw3;
#pragma unroll
        for (int k = 0; k < 4; ++k) {
            float2 f0 = __half22float2(h0[k]);
            float2 f1 = __half22float2(h1[k]);
            float2 f2 = __half22float2(h2[k]);
            float2 f3 = __half22float2(h3[k]);
            a[2 * k]     += (f0.x + f1.x) + (f2.x + f3.x);
            a[2 * k + 1] += (f0.y + f1.y) + (f2.y + f3.y);
        }
    }
    for (; e + 8 <= r1; e += 8) {
        int s0 = col[e + p];
        uint4 raw0 = *((const uint4*)(A16 + (size_t)s0 * HID) + hc);
        const __half2* h0 = (const __half2*)&raw0;
#pragma unroll
        for (int k = 0; k < 4; ++k) {
            float2 f0 = __half22float2(h0[k]);
            a[2 * k]     += f0.x;
            a[2 * k + 1] += f0.y;
        }
    }
    if (e + p < r1) {
        int s0 = col[e + p];
        uint4 raw0 = *((const uint4*)(A16 + (size_t)s0 * HID) + hc);
        const __half2* h0 = (const __half2*)&raw0;
#pragma unroll
        for (int k = 0; k < 4; ++k) {
            float2 f0 = __half22float2(h0[k]);
            a[2 * k]     += f0.x;
            a[2 * k + 1] += f0.y;
        }
    }
#pragma unroll
    for (int k = 0; k < 8; ++k) {
        a[k] += __shfl_xor(a[k], 2, 64);
        a[k] += __shfl_xor(a[k], 4, 64);
        a[k] += __shfl_xor(a[k], 8, 64);
    }
    if (l < 2) {
        float4* d0 = (float4*)&sAcc[gg][hc * 8];
        d0[0] = make_float4(a[0], a[1], a[2], a[3]);
        d0[1] = make_float4(a[4], a[5], a[6], a[7]);
    }
    __syncthreads();

    float dv = valid ? dinv[i] : 0.f;
    float self = valid ? __half2float(A16[(size_t)i * HID + l]) : 0.f;
    float v = dv * (sAcc[gg][l] + self) + sb[l];
    float h1 = (v > 0.f) ? v : expm1f(v);

    int lanebase = (threadIdx.x & 63) & ~15;
    float hp = 0.f;
#pragma unroll
    for (int k = 0; k < HID; ++k)
        hp += __shfl(h1, lanebase + k, 64) * sW[k * HID + l];
    float pz = dv * hp * sw[l];
#pragma unroll
    for (int off = 8; off > 0; off >>= 1) pz += __shfl_xor(pz, off, 64);
    if (l == 0 && valid) z[i] = pz;
}

// ---- layer 2: scalar z gather, 8 partials in flight + final affine ----
__global__ __launch_bounds__(256) void k_gfin4(const unsigned int* __restrict__ rowptr,
                                               const int* __restrict__ col,
                                               const float* __restrict__ z,
                                               const float* __restrict__ dinv,
                                               const float* __restrict__ b2,
                                               const float* __restrict__ Wl,
                                               const float* __restrict__ bl,
                                               float* __restrict__ out, int n) {
    __shared__ float sc0;
    if (threadIdx.x == 0) {
        float c = 0.f;
#pragma unroll
        for (int k = 0; k < HID; ++k) c += b2[k] * Wl[k];
        sc0 = c + bl[0];
    }
    __syncthreads();

    int i = blockIdx.x * blockDim.x + threadIdx.x;
    if (i >= n) return;

    unsigned int r0 = rowptr[i];
    unsigned int r1 = rowptr[i + 1];
    float s0 = 0.f, s1 = 0.f, s2 = 0.f, s3 = 0.f;
    float s4 = 0.f, s5 = 0.f, s6 = 0.f, s7 = 0.f;
    unsigned int e = r0;
    for (; e + 8 <= r1; e += 8) {
        s0 += z[col[e + 0]]; s1 += z[col[e + 1]];
        s2 += z[col[e + 2]]; s3 += z[col[e + 3]];
        s4 += z[col[e + 4]]; s5 += z[col[e + 5]];
        s6 += z[col[e + 6]]; s7 += z[col[e + 7]];
    }
    for (; e < r1; ++e) s0 += z[col[e]];
    float s = ((s0 + s1) + (s2 + s3)) + ((s4 + s5) + (s6 + s7));
    out[i] = dinv[i] * (s + z[i]) + sc0;
}

extern "C" void kernel_launch(void* const* d_in, const int* in_sizes, int n_in,
                              void* d_out, int out_size, void* d_ws, size_t ws_size,
                              hipStream_t stream) {
    const int*   x        = (const int*)d_in[0];
    const int*   ei       = (const int*)d_in[1];   // int32 per harness conversion
    const float* birth_t  = (const float*)d_in[2];
    const float* gender_t = (const float*)d_in[3];
    const float* symp_t   = (const float*)d_in[4];
    const float* W1       = (const float*)d_in[5];
    const float* b1       = (const float*)d_in[6];
    const float* W2       = (const float*)d_in[7];
    const float* b2       = (const float*)d_in[8];
    const float* Wl       = (const float*)d_in[9];
    const float* bl       = (const float*)d_in[10];
    float*       out      = (float*)d_out;

    const int n  = in_sizes[0] / XCOLS;
    const int nE = in_sizes[1] / 2;
    const int* src = ei;
    const int* tgt = ei + nE;

    const int nbuck = (n + BSZ - 1) >> BSHIFT;            // 782
    const int gb1   = (nE + EPB - 1) / EPB;               // 782

    // workspace layout (256B aligned slices)
    char* ws = (char*)d_ws;
    size_t off = 0;
    auto alloc = [&](size_t bytes) { char* p = ws + off; off = (off + bytes + 255) & ~(size_t)255; return p; };
    unsigned int* L      = (unsigned int*)alloc((size_t)(nbuck + 1) * gb1 * 4);
    unsigned int* R      = (unsigned int*)alloc((size_t)(nbuck + 1) * 4);
    int*          bp     = (int*)alloc((size_t)gb1 * EPB * 4);
    int*          col    = (int*)alloc((size_t)nE * 4);
    unsigned int* rowptr = (unsigned int*)alloc(((size_t)n + 1) * 4);
    float*        dinv   = (float*)alloc((size_t)n * 4);
    __half*       A16    = (__half*)alloc((size_t)n * HID * 2);
    float*        z      = (float*)alloc((size_t)n * 4);

    const int BLK = 256;
    const int gN    = (n + BLK - 1) / BLK;
    const int gNode = (n + 15) / 16;

    k_scat <<<gb1, BLK, 0, stream>>>(tgt, src, L, bp, nE, gb1, nbuck);
    k_rsum <<<nbuck + 1, BLK, 0, stream>>>(L, R, gb1);
    k_bcsr <<<nbuck, 512, 0, stream>>>(L, R, bp, x, birth_t, gender_t, symp_t, W1,
                                       rowptr, col, dinv, A16, n, gb1);
    k_gmid5<<<gNode, BLK, 0, stream>>>(rowptr, col, A16, dinv, W2, b1, Wl, z, n);
    k_gfin4<<<gN, BLK, 0, stream>>>(rowptr, col, z, dinv, b2, Wl, bl, out, n);
}

// Round 23
// 215.380 us; speedup vs baseline: 1.1292x; 1.1292x over previous
//
#include <hip/hip_runtime.h>
#include <hip/hip_fp16.h>
#include <math.h>

#define EMB 32
#define HID 16
#define BY 4
#define NSYMP 15
#define NOPT 3
#define XCOLS (BY + 1 + NSYMP)   // 20

#define BSHIFT 8                 // 256 nodes per tgt bucket
#define BSZ 256
#define EPB 8192                 // edges per scat block (gb1 = 782)
#define NBCAP 1024               // padded bin capacity (>= nbuck+1 = 783)
#define SPT 4                    // scan items per thread in scat (1024/256)
#define SPT2 2                   // segments per thread in bcsr (512 thr, covers gb1 <= 1024)
#define LSTCAP 9216              // staged edges per bucket (mean 8184, +11 sigma)

__device__ __forceinline__ unsigned int wave_incl_scan(unsigned int v, int lane) {
#pragma unroll
    for (int off = 1; off < 64; off <<= 1) {
        unsigned int u = __shfl_up(v, off, 64);
        if (lane >= off) v += u;
    }
    return v;
}

// ---- fused hist + local scan + block-local scatter ----
__global__ __launch_bounds__(256) void k_scat(const int* __restrict__ tgt,
                                              const int* __restrict__ src,
                                              unsigned int* __restrict__ L,
                                              int* __restrict__ bp,
                                              int nE, int gb1, int nbuck) {
    __shared__ int bpv[EPB];                 // 32 KB staged payload
    __shared__ unsigned int cur[NBCAP];      // 4 KB hist -> cursors
    __shared__ unsigned int wsum[4];
    int b = blockIdx.x, tid = threadIdx.x;
    int lane = tid & 63, wid = tid >> 6;
    for (int k = tid; k < NBCAP; k += 256) cur[k] = 0;
    __syncthreads();
    int e0 = b * EPB;
    int ecnt = min(EPB, nE - e0);

    for (int k = tid; k < ecnt; k += 256)
        atomicAdd(&cur[(unsigned)tgt[e0 + k] >> BSHIFT], 1u);
    __syncthreads();

    unsigned int lv[SPT]; unsigned int tsum = 0;
#pragma unroll
    for (int k = 0; k < SPT; ++k) {
        int f = SPT * tid + k;
        lv[k] = tsum; tsum += cur[f];
    }
    unsigned int incl = wave_incl_scan(tsum, lane);
    if (lane == 63) wsum[wid] = incl;
    __syncthreads();
    unsigned int woff = 0;
    for (int w = 0; w < wid; ++w) woff += wsum[w];
    unsigned int excl = woff + incl - tsum;
    __syncthreads();
#pragma unroll
    for (int k = 0; k < SPT; ++k) {
        int f = SPT * tid + k;
        unsigned int v = excl + lv[k];
        cur[f] = v;
        if (f <= nbuck) L[(size_t)f * gb1 + b] = v;
    }
    __syncthreads();

    for (int k = tid; k < ecnt; k += 256) {
        int t = tgt[e0 + k];
        int q = (unsigned)t >> BSHIFT;
        unsigned int lpos = atomicAdd(&cur[q], 1u);
        bpv[lpos] = (src[e0 + k] << BSHIFT) | (t & (BSZ - 1));
    }
    __syncthreads();

    for (int k = tid; k < ecnt; k += 256)
        bp[e0 + k] = bpv[k];
}

// ---- row sums of L -> global bucket starts R[q] ----
__global__ __launch_bounds__(256) void k_rsum(const unsigned int* __restrict__ L,
                                              unsigned int* __restrict__ R, int gb1) {
    __shared__ unsigned int s[256];
    int q = blockIdx.x, tid = threadIdx.x;
    unsigned int t = 0;
    for (int b = tid; b < gb1; b += 256) t += L[(size_t)q * gb1 + b];
    s[tid] = t; __syncthreads();
    for (int off = 128; off > 0; off >>= 1) {
        if (tid < off) s[tid] += s[tid + off];
        __syncthreads();
    }
    if (tid == 0) R[q] = s[0];
}

// ---- level-2 + embed fusion: segment gather with FUSED hist, fine sort,
//      LDS-staged col write, rowptr, dinv, then embedding + h@W1 -> fp16 ----
__global__ __launch_bounds__(512) void k_bcsr(const unsigned int* __restrict__ L,
                                              const unsigned int* __restrict__ R,
                                              const int* __restrict__ bp,
                                              const int* __restrict__ x,
                                              const float* __restrict__ birth_t,
                                              const float* __restrict__ gender_t,
                                              const float* __restrict__ symp_t,
                                              const float* __restrict__ W1,
                                              unsigned int* __restrict__ rowptr,
                                              int* __restrict__ col,
                                              float* __restrict__ dinv,
                                              __half* __restrict__ A16,
                                              int n, int gb1) {
    __shared__ int lst[LSTCAP];              // 36 KB
    __shared__ unsigned int h[BSZ];
    __shared__ unsigned int cu[BSZ];
    __shared__ unsigned int wsum[8];
    __shared__ float sB[BY * EMB];
    __shared__ float sG[2 * EMB];
    __shared__ float sS[NSYMP * NOPT * EMB];
    __shared__ float sW1[EMB * HID];
    int q = blockIdx.x, tid = threadIdx.x;
    int lane = tid & 63, wid = tid >> 6;

    // stage embed tables (512 threads)
    for (int k = tid; k < BY * EMB; k += 512) sB[k] = birth_t[k];
    for (int k = tid; k < 2 * EMB; k += 512) sG[k] = gender_t[k];
    for (int k = tid; k < NSYMP * NOPT * EMB; k += 512) sS[k] = symp_t[k];
    for (int k = tid; k < EMB * HID; k += 512) sW1[k] = W1[k];
    if (tid < BSZ) h[tid] = 0;

    const unsigned int* Lq0 = L + (size_t)q * gb1;
    const unsigned int* Lq1 = L + (size_t)(q + 1) * gb1;

    // phase A: per-thread segment lengths + prefix
    unsigned int st_[SPT2], ln_[SPT2], lvb[SPT2];
    unsigned int tsum = 0;
#pragma unroll
    for (int k = 0; k < SPT2; ++k) {
        int b = tid * SPT2 + k;
        unsigned int st = 0, ln = 0;
        if (b < gb1) { st = Lq0[b]; ln = Lq1[b] - st; }
        st_[k] = st; ln_[k] = ln; lvb[k] = tsum; tsum += ln;
    }
    unsigned int incl = wave_incl_scan(tsum, lane);
    if (lane == 63) wsum[wid] = incl;
    __syncthreads();                         // h[] init + wsum ready
    unsigned int woff = 0;
    for (int w = 0; w < wid; ++w) woff += wsum[w];
    unsigned int base = woff + incl - tsum;

    // copy + FUSED fine hist (values already in registers)
#pragma unroll
    for (int k = 0; k < SPT2; ++k) {
        const int* sp = bp + (size_t)(tid * SPT2 + k) * EPB + st_[k];
        unsigned int d = base + lvb[k];
        unsigned int ln = ln_[k];
        unsigned int j = 0;
        for (; j + 4 <= ln; j += 4) {
            int v0 = sp[j], v1 = sp[j + 1], v2 = sp[j + 2], v3 = sp[j + 3];
            lst[d + j] = v0; lst[d + j + 1] = v1;
            lst[d + j + 2] = v2; lst[d + j + 3] = v3;
            atomicAdd(&h[v0 & (BSZ - 1)], 1u);
            atomicAdd(&h[v1 & (BSZ - 1)], 1u);
            atomicAdd(&h[v2 & (BSZ - 1)], 1u);
            atomicAdd(&h[v3 & (BSZ - 1)], 1u);
        }
        for (; j < ln; ++j) {
            int v = sp[j];
            lst[d + j] = v;
            atomicAdd(&h[v & (BSZ - 1)], 1u);
        }
    }
    __syncthreads();

    unsigned int r0g = R[q];
    int cnt = (int)(R[q + 1] - r0g);

    // scan h -> cursors, rowptr, dinv
    float dvreg = 0.f;
    if (tid < BSZ) {
        unsigned int own = h[tid];
        unsigned int incl2 = wave_incl_scan(own, lane);
        if (lane == 63) wsum[wid] = incl2;
        cu[tid] = incl2 - own;   // wave-local exclusive
    }
    __syncthreads();
    if (tid < BSZ) {
        unsigned int woff2 = 0;
        for (int w = 0; w < wid; ++w) woff2 += wsum[w];
        unsigned int excl = woff2 + cu[tid];
        cu[tid] = excl;
        unsigned int own = h[tid];
        int i = (q << BSHIFT) + tid;
        if (i <= n) rowptr[i] = r0g + excl;
        if (i < n) {
            float d = (float)(own + 1u);
            float r = rsqrtf(d);
            r = r * (1.5f - 0.5f * d * r * r);
            dinv[i] = r;
            dvreg = r;
        }
    }
    __syncthreads();

    // phase C: scatter to col (4-wide) from lst
    {
        int k = tid;
        for (; k + 3 * 512 < cnt; k += 4 * 512) {
            int v0 = lst[k], v1 = lst[k + 512], v2 = lst[k + 1024], v3 = lst[k + 1536];
            unsigned int p0 = atomicAdd(&cu[v0 & (BSZ - 1)], 1u);
            unsigned int p1 = atomicAdd(&cu[v1 & (BSZ - 1)], 1u);
            unsigned int p2 = atomicAdd(&cu[v2 & (BSZ - 1)], 1u);
            unsigned int p3 = atomicAdd(&cu[v3 & (BSZ - 1)], 1u);
            col[r0g + p0] = (unsigned)v0 >> BSHIFT;
            col[r0g + p1] = (unsigned)v1 >> BSHIFT;
            col[r0g + p2] = (unsigned)v2 >> BSHIFT;
            col[r0g + p3] = (unsigned)v3 >> BSHIFT;
        }
        for (; k < cnt; k += 512) {
            int v = lst[k];
            unsigned int pos = atomicAdd(&cu[v & (BSZ - 1)], 1u);
            col[r0g + pos] = (unsigned)v >> BSHIFT;
        }
    }

    // phase D: embedding + h@W1 for this bucket's nodes (tid < 256)
    if (tid < BSZ) {
        int i = (q << BSHIFT) + tid;
        if (i < n) {
            const int* xr = x + (size_t)i * XCOLS;
            int xv[XCOLS];
#pragma unroll
            for (int k = 0; k < XCOLS; ++k) xv[k] = xr[k];
            int bi = 0;
#pragma unroll
            for (int k = 1; k < BY; ++k) if (xv[k] > xv[bi]) bi = k;
            int gi = xv[BY];
            float ssum[EMB];
#pragma unroll
            for (int k = 0; k < EMB; ++k) ssum[k] = 0.f;
#pragma unroll
            for (int j = 0; j < NSYMP; ++j) {
                const float* row = &sS[(j * NOPT + xv[BY + 1 + j]) * EMB];
#pragma unroll
                for (int k = 0; k < EMB; ++k) ssum[k] += row[k];
            }
            float hh[EMB];
#pragma unroll
            for (int k = 0; k < EMB; ++k)
                hh[k] = (sB[bi * EMB + k] + sG[gi * EMB + k] + ssum[k] * (1.f / 15.f)) * (1.f / 3.f);
            float hp[HID];
#pragma unroll
            for (int j = 0; j < HID; ++j) hp[j] = 0.f;
#pragma unroll
            for (int k = 0; k < EMB; ++k) {
                float hv = hh[k];
#pragma unroll
                for (int j = 0; j < HID; ++j) hp[j] += hv * sW1[k * HID + j];
            }
            __half2 t2[8];
#pragma unroll
            for (int j = 0; j < 8; ++j)
                t2[j] = __floats2half2_rn(dvreg * hp[2 * j], dvreg * hp[2 * j + 1]);
            uint4* o = (uint4*)(A16 + (size_t)i * HID);
            o[0] = *(uint4*)&t2[0];
            o[1] = *(uint4*)&t2[4];
        }
    }
}

// ---- layer 1: lane-pair fp16 CSR gather (4 rows in flight) + ELU + W2 + z ----
__global__ __launch_bounds__(256) void k_gmid5(const unsigned int* __restrict__ rowptr,
                                               const int* __restrict__ col,
                                               const __half* __restrict__ A16,
                                               const float* __restrict__ dinv,
                                               const float* __restrict__ W2,
                                               const float* __restrict__ b1,
                                               const float* __restrict__ Wl,
                                               float* __restrict__ z, int n) {
    __shared__ float sW[HID * HID];
    __shared__ float sb[HID];
    __shared__ float sw[HID];
    __shared__ float sAcc[16][HID];
    if (threadIdx.x < HID * HID) sW[threadIdx.x] = W2[threadIdx.x];
    if (threadIdx.x < HID) { sb[threadIdx.x] = b1[threadIdx.x]; sw[threadIdx.x] = Wl[threadIdx.x]; }
    __syncthreads();

    int gg = threadIdx.x >> 4;
    int l  = threadIdx.x & 15;
    int p  = l >> 1;
    int hc = l & 1;
    int i = blockIdx.x * 16 + gg;
    bool valid = (i < n);

    unsigned int r0 = 0, r1 = 0;
    if (valid) { r0 = rowptr[i]; r1 = rowptr[i + 1]; }

    float a[8];
#pragma unroll
    for (int k = 0; k < 8; ++k) a[k] = 0.f;

    unsigned int e = r0;
    for (; e + 32 <= r1; e += 32) {
        int s0 = col[e + p];
        int s1 = col[e + 8 + p];
        int s2 = col[e + 16 + p];
        int s3 = col[e + 24 + p];
        uint4 raw0 = *((const uint4*)(A16 + (size_t)s0 * HID) + hc);
        uint4 raw1 = *((const uint4*)(A16 + (size_t)s1 * HID) + hc);
        uint4 raw2 = *((const uint4*)(A16 + (size_t)s2 * HID) + hc);
        uint4 raw3 = *((const uint4*)(A16 + (size_t)s3 * HID) + hc);
        const __half2* h0 = (const __half2*)&raw0;
        const __half2* h1 = (const __half2*)&raw1;
        const __half2* h2 = (const __half2*)&raw2;
        const __half2* h3 = (const __half2*)&raw3;
#pragma unroll
        for (int k = 0; k < 4; ++k) {
            float2 f0 = __half22float2(h0[k]);
            float2 f1 = __half22float2(h1[k]);
            float2 f2 = __half22float2(h2[k]);
            float2 f3 = __half22float2(h3[k]);
            a[2 * k]     += (f0.x + f1.x) + (f2.x + f3.x);
            a[2 * k + 1] += (f0.y + f1.y) + (f2.y + f3.y);
        }
    }
    for (; e + 8 <= r1; e += 8) {
        int s0 = col[e + p];
        uint4 raw0 = *((const uint4*)(A16 + (size_t)s0 * HID) + hc);
        const __half2* h0 = (const __half2*)&raw0;
#pragma unroll
        for (int k = 0; k < 4; ++k) {
            float2 f0 = __half22float2(h0[k]);
            a[2 * k]     += f0.x;
            a[2 * k + 1] += f0.y;
        }
    }
    if (e + p < r1) {
        int s0 = col[e + p];
        uint4 raw0 = *((const uint4*)(A16 + (size_t)s0 * HID) + hc);
        const __half2* h0 = (const __half2*)&raw0;
#pragma unroll
        for (int k = 0; k < 4; ++k) {
            float2 f0 = __half22float2(h0[k]);
            a[2 * k]     += f0.x;
            a[2 * k + 1] += f0.y;
        }
    }
#pragma unroll
    for (int k = 0; k < 8; ++k) {
        a[k] += __shfl_xor(a[k], 2, 64);
        a[k] += __shfl_xor(a[k], 4, 64);
        a[k] += __shfl_xor(a[k], 8, 64);
    }
    if (l < 2) {
        float4* d0 = (float4*)&sAcc[gg][hc * 8];
        d0[0] = make_float4(a[0], a[1], a[2], a[3]);
        d0[1] = make_float4(a[4], a[5], a[6], a[7]);
    }
    __syncthreads();

    float dv = valid ? dinv[i] : 0.f;
    float self = valid ? __half2float(A16[(size_t)i * HID + l]) : 0.f;
    float v = dv * (sAcc[gg][l] + self) + sb[l];
    float h1 = (v > 0.f) ? v : expm1f(v);

    int lanebase = (threadIdx.x & 63) & ~15;
    float hp = 0.f;
#pragma unroll
    for (int k = 0; k < HID; ++k)
        hp += __shfl(h1, lanebase + k, 64) * sW[k * HID + l];
    float pz = dv * hp * sw[l];
#pragma unroll
    for (int off = 8; off > 0; off >>= 1) pz += __shfl_xor(pz, off, 64);
    if (l == 0 && valid) z[i] = pz;
}

// ---- layer 2: scalar z gather, 8 partials in flight + final affine ----
__global__ __launch_bounds__(256) void k_gfin4(const unsigned int* __restrict__ rowptr,
                                               const int* __restrict__ col,
                                               const float* __restrict__ z,
                                               const float* __restrict__ dinv,
                                               const float* __restrict__ b2,
                                               const float* __restrict__ Wl,
                                               const float* __restrict__ bl,
                                               float* __restrict__ out, int n) {
    __shared__ float sc0;
    if (threadIdx.x == 0) {
        float c = 0.f;
#pragma unroll
        for (int k = 0; k < HID; ++k) c += b2[k] * Wl[k];
        sc0 = c + bl[0];
    }
    __syncthreads();

    int i = blockIdx.x * blockDim.x + threadIdx.x;
    if (i >= n) return;

    unsigned int r0 = rowptr[i];
    unsigned int r1 = rowptr[i + 1];
    float s0 = 0.f, s1 = 0.f, s2 = 0.f, s3 = 0.f;
    float s4 = 0.f, s5 = 0.f, s6 = 0.f, s7 = 0.f;
    unsigned int e = r0;
    for (; e + 8 <= r1; e += 8) {
        s0 += z[col[e + 0]]; s1 += z[col[e + 1]];
        s2 += z[col[e + 2]]; s3 += z[col[e + 3]];
        s4 += z[col[e + 4]]; s5 += z[col[e + 5]];
        s6 += z[col[e + 6]]; s7 += z[col[e + 7]];
    }
    for (; e < r1; ++e) s0 += z[col[e]];
    float s = ((s0 + s1) + (s2 + s3)) + ((s4 + s5) + (s6 + s7));
    out[i] = dinv[i] * (s + z[i]) + sc0;
}

extern "C" void kernel_launch(void* const* d_in, const int* in_sizes, int n_in,
                              void* d_out, int out_size, void* d_ws, size_t ws_size,
                              hipStream_t stream) {
    const int*   x        = (const int*)d_in[0];
    const int*   ei       = (const int*)d_in[1];   // int32 per harness conversion
    const float* birth_t  = (const float*)d_in[2];
    const float* gender_t = (const float*)d_in[3];
    const float* symp_t   = (const float*)d_in[4];
    const float* W1       = (const float*)d_in[5];
    const float* b1       = (const float*)d_in[6];
    const float* W2       = (const float*)d_in[7];
    const float* b2       = (const float*)d_in[8];
    const float* Wl       = (const float*)d_in[9];
    const float* bl       = (const float*)d_in[10];
    float*       out      = (float*)d_out;

    const int n  = in_sizes[0] / XCOLS;
    const int nE = in_sizes[1] / 2;
    const int* src = ei;
    const int* tgt = ei + nE;

    const int nbuck = (n + BSZ - 1) >> BSHIFT;            // 782
    const int gb1   = (nE + EPB - 1) / EPB;               // 782

    // workspace layout (256B aligned slices)
    char* ws = (char*)d_ws;
    size_t off = 0;
    auto alloc = [&](size_t bytes) { char* p = ws + off; off = (off + bytes + 255) & ~(size_t)255; return p; };
    unsigned int* L      = (unsigned int*)alloc((size_t)(nbuck + 1) * gb1 * 4);
    unsigned int* R      = (unsigned int*)alloc((size_t)(nbuck + 1) * 4);
    int*          bp     = (int*)alloc((size_t)gb1 * EPB * 4);
    int*          col    = (int*)alloc((size_t)nE * 4);
    unsigned int* rowptr = (unsigned int*)alloc(((size_t)n + 1) * 4);
    float*        dinv   = (float*)alloc((size_t)n * 4);
    __half*       A16    = (__half*)alloc((size_t)n * HID * 2);
    float*        z      = (float*)alloc((size_t)n * 4);

    const int BLK = 256;
    const int gN    = (n + BLK - 1) / BLK;
    const int gNode = (n + 15) / 16;

    k_scat <<<gb1, BLK, 0, stream>>>(tgt, src, L, bp, nE, gb1, nbuck);
    k_rsum <<<nbuck + 1, BLK, 0, stream>>>(L, R, gb1);
    k_bcsr <<<nbuck, 512, 0, stream>>>(L, R, bp, x, birth_t, gender_t, symp_t, W1,
                                       rowptr, col, dinv, A16, n, gb1);
    k_gmid5<<<gNode, BLK, 0, stream>>>(rowptr, col, A16, dinv, W2, b1, Wl, z, n);
    k_gfin4<<<gN, BLK, 0, stream>>>(rowptr, col, z, dinv, b2, Wl, bl, out, n);
}